// Round 3
// baseline (23.651 us; speedup 1.0000x reference)
//
#include <hip/hip_runtime.h>

// OffsetSubtraction: out[b,w,f] = subed[b,w,f] - sub[b,clip(w+delay),f], delay
// in ORDER [0,+1..+d,-1..-d] minimizing |residual| (first-min tie-break, matching
// jnp.argmin). B=8, W=4096, F=64, fp32. Specialized d=8; generic fallback.
//
// XCD mapping: b = blockIdx.x & 7 -> with round-robin dispatch each XCD works
// one batch only (sub working set 1MB, L2-resident per XCD).

#define B_DIM 8
#define W_DIM 4096
#define FVEC  16              // 16 float4 per (b,w) row
#define RW    2               // w rows per thread
#define CHUNK_W 32            // w rows per block (16 pp * RW)
#define CHUNKS  (W_DIM / CHUNK_W)   // 128
#define NBLK    (B_DIM * CHUNKS)    // 1024 blocks

__device__ __forceinline__ float4 f4sub(float4 a, float4 b) {
    float4 r; r.x = a.x - b.x; r.y = a.y - b.y; r.z = a.z - b.z; r.w = a.w - b.w;
    return r;
}
// best = (|cand| < |best|) ? cand : best  (strict <: earlier element wins ties)
__device__ __forceinline__ void upd(float4& best, float4 cand) {
    best.x = (fabsf(cand.x) < fabsf(best.x)) ? cand.x : best.x;
    best.y = (fabsf(cand.y) < fabsf(best.y)) ? cand.y : best.y;
    best.z = (fabsf(cand.z) < fabsf(best.z)) ? cand.z : best.z;
    best.w = (fabsf(cand.w) < fabsf(best.w)) ? cand.w : best.w;
}
// left-wins merge of two order-partitioned chains
__device__ __forceinline__ float4 pick(float4 a, float4 b) {
    float4 r;
    r.x = (fabsf(b.x) < fabsf(a.x)) ? b.x : a.x;
    r.y = (fabsf(b.y) < fabsf(a.y)) ? b.y : a.y;
    r.z = (fabsf(b.z) < fabsf(a.z)) ? b.z : a.z;
    r.w = (fabsf(b.w) < fabsf(a.w)) ? b.w : a.w;
    return r;
}

__global__ __launch_bounds__(256) void offsub_kernel(
    const float4* __restrict__ subed,
    const float4* __restrict__ sub,
    const int* __restrict__ d_ptr,
    float4* __restrict__ out)
{
    const int d   = *d_ptr;
    const int tid = threadIdx.x;
    const int b     = blockIdx.x & 7;     // XCD-aligned batch
    const int chunk = blockIdx.x >> 3;
    const int fv = tid & (FVEC - 1);
    const int pp = tid >> 4;
    const int w0 = chunk * CHUNK_W + pp * RW;

    const size_t base   = (size_t)b * (W_DIM * FVEC) + fv;
    const size_t rowoff = base + (size_t)w0 * FVEC;

    if (__builtin_expect(d == 8, 1)) {
        const float4* ps = sub   + rowoff;
        const float4* pd = subed + rowoff;
        const float4 s0 = pd[0];
        const float4 s1 = pd[FVEC];

        float4 g[18];   // rows w0-8 .. w0+9, g[k] = row w0-8+k
        const bool interior = (w0 >= 8) && (w0 + 9 <= W_DIM - 1);  // wave-uniform
        if (interior) {
            #pragma unroll
            for (int k = 0; k < 18; ++k) g[k] = ps[(k - 8) * FVEC];  // imm offsets
        } else {
            #pragma unroll
            for (int k = 0; k < 18; ++k) {
                int wi = w0 - 8 + k;
                wi = wi < 0 ? 0 : (wi > W_DIM - 1 ? W_DIM - 1 : wi);
                g[k] = sub[base + (size_t)wi * FVEC];
            }
        }

        // r = 0: window g[0..16], center g[8]
        {
            const float4 s = s0;
            float4 c0 = f4sub(s, g[8]);                       // delta 0
            upd(c0, f4sub(s, g[9]));  upd(c0, f4sub(s, g[10]));
            upd(c0, f4sub(s, g[11])); upd(c0, f4sub(s, g[12]));  // +1..+4
            float4 c1 = f4sub(s, g[13]);
            upd(c1, f4sub(s, g[14])); upd(c1, f4sub(s, g[15]));
            upd(c1, f4sub(s, g[16]));                            // +5..+8
            float4 c2 = f4sub(s, g[7]);
            upd(c2, f4sub(s, g[6]));  upd(c2, f4sub(s, g[5]));
            upd(c2, f4sub(s, g[4]));                             // -1..-4
            float4 c3 = f4sub(s, g[3]);
            upd(c3, f4sub(s, g[2]));  upd(c3, f4sub(s, g[1]));
            upd(c3, f4sub(s, g[0]));                             // -5..-8
            out[rowoff] = pick(pick(c0, c1), pick(c2, c3));
        }
        // r = 1: window g[1..17], center g[9]
        {
            const float4 s = s1;
            float4 c0 = f4sub(s, g[9]);
            upd(c0, f4sub(s, g[10])); upd(c0, f4sub(s, g[11]));
            upd(c0, f4sub(s, g[12])); upd(c0, f4sub(s, g[13]));
            float4 c1 = f4sub(s, g[14]);
            upd(c1, f4sub(s, g[15])); upd(c1, f4sub(s, g[16]));
            upd(c1, f4sub(s, g[17]));
            float4 c2 = f4sub(s, g[8]);
            upd(c2, f4sub(s, g[7]));  upd(c2, f4sub(s, g[6]));
            upd(c2, f4sub(s, g[5]));
            float4 c3 = f4sub(s, g[4]);
            upd(c3, f4sub(s, g[3]));  upd(c3, f4sub(s, g[2]));
            upd(c3, f4sub(s, g[1]));
            out[rowoff + FVEC] = pick(pick(c0, c1), pick(c2, c3));
        }
    } else {
        // Generic-d fallback: runtime loop, same tie order.
        for (int r = 0; r < RW; ++r) {
            const int w = w0 + r;
            const float4 s = subed[base + (size_t)w * FVEC];
            float4 best = f4sub(s, sub[base + (size_t)w * FVEC]);
            for (int pass = 0; pass < 2; ++pass) {
                for (int dd = 1; dd <= d; ++dd) {
                    int wi = (pass == 0) ? min(w + dd, W_DIM - 1)
                                         : max(w - dd, 0);
                    upd(best, f4sub(s, sub[base + (size_t)wi * FVEC]));
                }
            }
            out[base + (size_t)w * FVEC] = best;
        }
    }
}

extern "C" void kernel_launch(void* const* d_in, const int* in_sizes, int n_in,
                              void* d_out, int out_size, void* d_ws, size_t ws_size,
                              hipStream_t stream)
{
    const float4* subed = (const float4*)d_in[0];
    const float4* sub   = (const float4*)d_in[1];
    const int*    dptr  = (const int*)d_in[2];
    float4* out = (float4*)d_out;

    offsub_kernel<<<NBLK, 256, 0, stream>>>(subed, sub, dptr, out);
}

// Round 4
// 16.497 us; speedup vs baseline: 1.4336x; 1.4336x over previous
//
#include <hip/hip_runtime.h>

// OffsetSubtraction: out[b,w,f] = subed[b,w,f] - sub[b,clip(w+delay),f], delay
// in ORDER [0,+1..+d,-1..-d] minimizing |residual| (first-min tie-break,
// matching jnp.argmin). B=8, W=4096, F=64, fp32. Specialized d=8 with generic
// fallback. Linear block mapping (R1's proven layout — NO XCD swizzle: R2
// showed concentrating batches per-XCD regresses 2.2x under the real dispatch).

#define B_DIM 8
#define W_DIM 4096
#define FVEC  16              // 16 float4 per (b,w) row
#define RW    2               // w rows per thread
#define WP    (W_DIM / RW)    // 2048 w-pairs
#define LOG2_WP 11
#define CHUNKS 128            // blocks per batch; each block covers 32 w

__device__ __forceinline__ float4 f4sub(float4 a, float4 b) {
    float4 r; r.x = a.x - b.x; r.y = a.y - b.y; r.z = a.z - b.z; r.w = a.w - b.w;
    return r;
}
// best = (|cand| < |best|) ? cand : best  (strict <: earlier delay wins ties)
__device__ __forceinline__ void upd(float4& best, float4 cand) {
    best.x = (fabsf(cand.x) < fabsf(best.x)) ? cand.x : best.x;
    best.y = (fabsf(cand.y) < fabsf(best.y)) ? cand.y : best.y;
    best.z = (fabsf(cand.z) < fabsf(best.z)) ? cand.z : best.z;
    best.w = (fabsf(cand.w) < fabsf(best.w)) ? cand.w : best.w;
}
// left-wins merge of two order-partitioned chains
__device__ __forceinline__ float4 pick(float4 a, float4 b) {
    float4 r;
    r.x = (fabsf(b.x) < fabsf(a.x)) ? b.x : a.x;
    r.y = (fabsf(b.y) < fabsf(a.y)) ? b.y : a.y;
    r.z = (fabsf(b.z) < fabsf(a.z)) ? b.z : a.z;
    r.w = (fabsf(b.w) < fabsf(a.w)) ? b.w : a.w;
    return r;
}

__global__ __launch_bounds__(256) void offsub_kernel(
    const float4* __restrict__ subed,
    const float4* __restrict__ sub,
    const int* __restrict__ d_ptr,
    float4* __restrict__ out)
{
    const int tid  = blockIdx.x * 256 + threadIdx.x;
    const int d    = *d_ptr;

    const int fv   = tid & (FVEC - 1);
    const int rest = tid >> 4;
    const int p    = rest & (WP - 1);
    const int b    = rest >> LOG2_WP;
    const int w0   = p * RW;

    const size_t base   = (size_t)b * (W_DIM * FVEC) + fv;
    const size_t rowoff = base + (size_t)w0 * FVEC;

    if (__builtin_expect(d == 8, 1)) {
        const float4* pd = subed + rowoff;
        const float4 s0 = pd[0];
        const float4 s1 = pd[FVEC];

        float4 g[18];   // rows w0-8 .. w0+9; g[k] = row w0-8+k
        const int chunk = blockIdx.x & (CHUNKS - 1);
        if (__builtin_expect(chunk != 0 && chunk != CHUNKS - 1, 1)) {
            // Block-uniform interior: one base pointer, compile-time offsets.
            const float4* ps = sub + rowoff;
            #pragma unroll
            for (int k = 0; k < 18; ++k) g[k] = ps[(k - 8) * FVEC];
        } else {
            #pragma unroll
            for (int k = 0; k < 18; ++k) {
                int wi = w0 - 8 + k;
                wi = wi < 0 ? 0 : (wi > W_DIM - 1 ? W_DIM - 1 : wi);
                g[k] = sub[base + (size_t)wi * FVEC];
            }
        }

        // r = 0: center g[8].  Chains partitioned in delay order
        // [0,+1..+4][+5..+8][-1..-4][-5..-8]; left-wins merges keep order.
        {
            const float4 s = s0;
            float4 c0 = f4sub(s, g[8]);
            upd(c0, f4sub(s, g[9]));  upd(c0, f4sub(s, g[10]));
            upd(c0, f4sub(s, g[11])); upd(c0, f4sub(s, g[12]));
            float4 c1 = f4sub(s, g[13]);
            upd(c1, f4sub(s, g[14])); upd(c1, f4sub(s, g[15]));
            upd(c1, f4sub(s, g[16]));
            float4 c2 = f4sub(s, g[7]);
            upd(c2, f4sub(s, g[6]));  upd(c2, f4sub(s, g[5]));
            upd(c2, f4sub(s, g[4]));
            float4 c3 = f4sub(s, g[3]);
            upd(c3, f4sub(s, g[2]));  upd(c3, f4sub(s, g[1]));
            upd(c3, f4sub(s, g[0]));
            out[rowoff] = pick(pick(c0, c1), pick(c2, c3));
        }
        // r = 1: center g[9].
        {
            const float4 s = s1;
            float4 c0 = f4sub(s, g[9]);
            upd(c0, f4sub(s, g[10])); upd(c0, f4sub(s, g[11]));
            upd(c0, f4sub(s, g[12])); upd(c0, f4sub(s, g[13]));
            float4 c1 = f4sub(s, g[14]);
            upd(c1, f4sub(s, g[15])); upd(c1, f4sub(s, g[16]));
            upd(c1, f4sub(s, g[17]));
            float4 c2 = f4sub(s, g[8]);
            upd(c2, f4sub(s, g[7]));  upd(c2, f4sub(s, g[6]));
            upd(c2, f4sub(s, g[5]));
            float4 c3 = f4sub(s, g[4]);
            upd(c3, f4sub(s, g[3]));  upd(c3, f4sub(s, g[2]));
            upd(c3, f4sub(s, g[1]));
            out[rowoff + FVEC] = pick(pick(c0, c1), pick(c2, c3));
        }
    } else {
        // Generic-d fallback: runtime loop, same tie order.
        for (int r = 0; r < RW; ++r) {
            const int w = w0 + r;
            const float4 s = subed[base + (size_t)w * FVEC];
            float4 best = f4sub(s, sub[base + (size_t)w * FVEC]);
            for (int pass = 0; pass < 2; ++pass) {
                for (int dd = 1; dd <= d; ++dd) {
                    int wi = (pass == 0) ? min(w + dd, W_DIM - 1)
                                         : max(w - dd, 0);
                    upd(best, f4sub(s, sub[base + (size_t)wi * FVEC]));
                }
            }
            out[base + (size_t)w * FVEC] = best;
        }
    }
}

extern "C" void kernel_launch(void* const* d_in, const int* in_sizes, int n_in,
                              void* d_out, int out_size, void* d_ws, size_t ws_size,
                              hipStream_t stream)
{
    const float4* subed = (const float4*)d_in[0];
    const float4* sub   = (const float4*)d_in[1];
    const int*    dptr  = (const int*)d_in[2];
    float4* out = (float4*)d_out;

    const int total = B_DIM * WP * FVEC;   // 262144 threads
    const int block = 256;
    const int grid  = (total + block - 1) / block;   // 1024 blocks

    offsub_kernel<<<grid, block, 0, stream>>>(subed, sub, dptr, out);
}

// Round 5
// 11.838 us; speedup vs baseline: 1.9978x; 1.3935x over previous
//
#include <hip/hip_runtime.h>

// OffsetSubtraction: out[b,w,f] = subed[b,w,f] - sub[b,clip(w+delay),f], delay
// in ORDER [0,+1..+d,-1..-d] minimizing |residual| (first-min tie-break,
// matching jnp.argmin). B=8, W=4096, F=64, fp32. Specialized d=8 with generic
// fallback.
//
// R4: RW=4 rows/thread with a 20-row register window (rows w0-8..w0+11) —
// 7 VMEM/output vs R1's 11, logical L2 reads 96 B/output vs 176 B.
// Linear block mapping (R2 proved XCD-concentration regresses 2.2x).
// Per-thread clamped addressing + sequential select chain (R1's proven shape).

#define B_DIM 8
#define W_DIM 4096
#define FVEC  16              // 16 float4 per (b,w) row
#define RW    4               // w rows per thread
#define WPB   64              // w rows per block (16 pp * RW)
#define CHUNKS (W_DIM / WPB)  // 64 chunks per batch
#define NBLK   (B_DIM * CHUNKS)  // 512 blocks

__device__ __forceinline__ float4 f4sub(float4 a, float4 b) {
    float4 r; r.x = a.x - b.x; r.y = a.y - b.y; r.z = a.z - b.z; r.w = a.w - b.w;
    return r;
}
// best = (|cand| < |best|) ? cand : best  (strict <: earlier delay wins ties)
__device__ __forceinline__ void upd(float4& best, float4 cand) {
    best.x = (fabsf(cand.x) < fabsf(best.x)) ? cand.x : best.x;
    best.y = (fabsf(cand.y) < fabsf(best.y)) ? cand.y : best.y;
    best.z = (fabsf(cand.z) < fabsf(best.z)) ? cand.z : best.z;
    best.w = (fabsf(cand.w) < fabsf(best.w)) ? cand.w : best.w;
}

__global__ __launch_bounds__(256) void offsub_kernel(
    const float4* __restrict__ subed,
    const float4* __restrict__ sub,
    const int* __restrict__ d_ptr,
    float4* __restrict__ out)
{
    const int d  = *d_ptr;
    const int fv = threadIdx.x & (FVEC - 1);
    const int pp = threadIdx.x >> 4;
    const int chunk = blockIdx.x & (CHUNKS - 1);
    const int b     = blockIdx.x >> 6;          // linear: high bits = batch
    const int w0    = chunk * WPB + pp * RW;

    const size_t base = (size_t)b * (W_DIM * FVEC) + fv;

    if (__builtin_expect(d == 8, 1)) {
        // Register rolling window: rows w0-8 .. w0+RW-1+8 (20 rows, clamped).
        float4 g[16 + RW];
        #pragma unroll
        for (int k = 0; k < 16 + RW; ++k) {
            int wi = w0 - 8 + k;
            wi = wi < 0 ? 0 : (wi > W_DIM - 1 ? W_DIM - 1 : wi);
            g[k] = sub[base + (size_t)wi * FVEC];
        }
        #pragma unroll
        for (int r = 0; r < RW; ++r) {
            const int w = w0 + r;
            const float4 s = subed[base + (size_t)w * FVEC];
            float4 best = f4sub(s, g[r + 8]);          // delay 0
            #pragma unroll
            for (int dd = 1; dd <= 8; ++dd)            // +1..+8
                upd(best, f4sub(s, g[r + 8 + dd]));
            #pragma unroll
            for (int dd = 1; dd <= 8; ++dd)            // -1..-8
                upd(best, f4sub(s, g[r + 8 - dd]));
            out[base + (size_t)w * FVEC] = best;
        }
    } else {
        // Generic-d fallback: runtime loop, same tie order.
        for (int r = 0; r < RW; ++r) {
            const int w = w0 + r;
            const float4 s = subed[base + (size_t)w * FVEC];
            float4 best = f4sub(s, sub[base + (size_t)w * FVEC]);
            for (int pass = 0; pass < 2; ++pass) {
                for (int dd = 1; dd <= d; ++dd) {
                    int wi = (pass == 0) ? min(w + dd, W_DIM - 1)
                                         : max(w - dd, 0);
                    upd(best, f4sub(s, sub[base + (size_t)wi * FVEC]));
                }
            }
            out[base + (size_t)w * FVEC] = best;
        }
    }
}

extern "C" void kernel_launch(void* const* d_in, const int* in_sizes, int n_in,
                              void* d_out, int out_size, void* d_ws, size_t ws_size,
                              hipStream_t stream)
{
    const float4* subed = (const float4*)d_in[0];
    const float4* sub   = (const float4*)d_in[1];
    const int*    dptr  = (const int*)d_in[2];
    float4* out = (float4*)d_out;

    offsub_kernel<<<NBLK, 256, 0, stream>>>(subed, sub, dptr, out);
}

// Round 6
// 10.854 us; speedup vs baseline: 2.1789x; 1.0907x over previous
//
#include <hip/hip_runtime.h>

// OffsetSubtraction: out[b,w,f] = subed[b,w,f] - sub[b,clip(w+delay),f], delay
// in ORDER [0,+1..+d,-1..-d] minimizing |residual| (first-min tie-break,
// matching jnp.argmin). B=8, W=4096, F=64, fp32. Specialized d=8 with generic
// fallback.
//
// R5 = R1 replication probe (best measured: 10.85 us) + load-order polish.
// RW=2, 1024 blocks, per-thread clamped addressing, sequential select chain.
// History: R2 XCD-concentration regressed 2.2x (undefined dispatch mapping);
// R3 imm-offset/tree variant +5.6us (unexplained, abandoned); R4 RW=4 cut
// traffic 1.8x but was +1us => time is insensitive to per-thread memory work
// => overhead/latency floor hypothesis. This round pins the floor.

#define B_DIM 8
#define W_DIM 4096
#define FVEC  16              // 16 float4 per (b,w) row
#define RW    2               // w rows per thread
#define WP    (W_DIM / RW)    // 2048 w-pairs
#define LOG2_WP 11

__device__ __forceinline__ float4 f4sub(float4 a, float4 b) {
    float4 r; r.x = a.x - b.x; r.y = a.y - b.y; r.z = a.z - b.z; r.w = a.w - b.w;
    return r;
}
// best = (|cand| < |best|) ? cand : best  (strict <: earlier delay wins ties)
__device__ __forceinline__ void upd(float4& best, float4 cand) {
    best.x = (fabsf(cand.x) < fabsf(best.x)) ? cand.x : best.x;
    best.y = (fabsf(cand.y) < fabsf(best.y)) ? cand.y : best.y;
    best.z = (fabsf(cand.z) < fabsf(best.z)) ? cand.z : best.z;
    best.w = (fabsf(cand.w) < fabsf(best.w)) ? cand.w : best.w;
}

__global__ __launch_bounds__(256) void offsub_kernel(
    const float4* __restrict__ subed,
    const float4* __restrict__ sub,
    const int* __restrict__ d_ptr,
    float4* __restrict__ out)
{
    const int tid = blockIdx.x * 256 + threadIdx.x;
    const int d   = *d_ptr;

    const int fv   = tid & (FVEC - 1);
    const int rest = tid >> 4;
    const int p    = rest & (WP - 1);
    const int b    = rest >> LOG2_WP;
    const int w0   = p * RW;

    const size_t base = (size_t)b * (W_DIM * FVEC) + fv;

    if (__builtin_expect(d == 8, 1)) {
        // subed first (first-use is earliest in the select chain)
        const float4 s0 = subed[base + (size_t)w0 * FVEC];
        const float4 s1 = subed[base + (size_t)(w0 + 1) * FVEC];

        // Window rows w0-8 .. w0+9 (18 rows, clamped), g[k] = row w0-8+k.
        // Emit loads in consumption order: centers, +side, -side, tail.
        float4 g[18];
        {
            #pragma unroll
            for (int k = 8; k <= 17; ++k) {      // w0 .. w0+9 (centers + plus-side)
                int wi = w0 - 8 + k;
                wi = wi > W_DIM - 1 ? W_DIM - 1 : wi;
                g[k] = sub[base + (size_t)wi * FVEC];
            }
            #pragma unroll
            for (int k = 7; k >= 0; --k) {       // w0-1 .. w0-8 (minus-side)
                int wi = w0 - 8 + k;
                wi = wi < 0 ? 0 : wi;
                g[k] = sub[base + (size_t)wi * FVEC];
            }
        }

        // r = 0: center g[8]; sequential chain, delay order 0,+1..+8,-1..-8
        {
            const float4 s = s0;
            float4 best = f4sub(s, g[8]);
            #pragma unroll
            for (int dd = 1; dd <= 8; ++dd) upd(best, f4sub(s, g[8 + dd]));
            #pragma unroll
            for (int dd = 1; dd <= 8; ++dd) upd(best, f4sub(s, g[8 - dd]));
            out[base + (size_t)w0 * FVEC] = best;
        }
        // r = 1: center g[9]
        {
            const float4 s = s1;
            float4 best = f4sub(s, g[9]);
            #pragma unroll
            for (int dd = 1; dd <= 8; ++dd) upd(best, f4sub(s, g[9 + dd]));
            #pragma unroll
            for (int dd = 1; dd <= 8; ++dd) upd(best, f4sub(s, g[9 - dd]));
            out[base + (size_t)(w0 + 1) * FVEC] = best;
        }
    } else {
        // Generic-d fallback: runtime loop, same tie order.
        for (int r = 0; r < RW; ++r) {
            const int w = w0 + r;
            const float4 s = subed[base + (size_t)w * FVEC];
            float4 best = f4sub(s, sub[base + (size_t)w * FVEC]);
            for (int pass = 0; pass < 2; ++pass) {
                for (int dd = 1; dd <= d; ++dd) {
                    int wi = (pass == 0) ? min(w + dd, W_DIM - 1)
                                         : max(w - dd, 0);
                    upd(best, f4sub(s, sub[base + (size_t)wi * FVEC]));
                }
            }
            out[base + (size_t)w * FVEC] = best;
        }
    }
}

extern "C" void kernel_launch(void* const* d_in, const int* in_sizes, int n_in,
                              void* d_out, int out_size, void* d_ws, size_t ws_size,
                              hipStream_t stream)
{
    const float4* subed = (const float4*)d_in[0];
    const float4* sub   = (const float4*)d_in[1];
    const int*    dptr  = (const int*)d_in[2];
    float4* out = (float4*)d_out;

    const int total = B_DIM * WP * FVEC;   // 262144 threads
    const int block = 256;
    const int grid  = (total + block - 1) / block;   // 1024 blocks

    offsub_kernel<<<grid, block, 0, stream>>>(subed, sub, dptr, out);
}